// Round 1
// baseline (8277.869 us; speedup 1.0000x reference)
//
#include <hip/hip_runtime.h>
#include <math.h>

#define EMB  1024
#define HID  1024
#define BATCH  64
#define SEQ   512

// ---------------------------------------------------------------------------
// Kernel A: x_proj GEMM.  out[(s*64+b)*1024 + n] = sum_k embeds[b][s][k]*W_ih[n][k]
//                                                  + b_ih[n] + b_hh[n]
// Plain fp32 tiled GEMM (no fp32 MFMA on CDNA4). 64x64 tile, 256 threads,
// 4x4 micro-tile per thread, K staged in 16-wide slabs (transposed in LDS).
// ---------------------------------------------------------------------------
__global__ __launch_bounds__(256) void xproj_gemm(
    const float* __restrict__ A,      // embeds, (B*S) x EMB row-major, m = b*512+s
    const float* __restrict__ W,      // W_ih, HID x EMB row-major
    const float* __restrict__ b_ih,
    const float* __restrict__ b_hh,
    float* __restrict__ out)          // (S, B, HID)
{
    // +4 pad: row stride 68 floats = 272B (16B aligned), banks rotate by 4/row
    __shared__ float As[16][68];
    __shared__ float Ws[16][68];

    const int tid = threadIdx.x;
    const int tx  = tid & 15;          // n micro index
    const int ty  = tid >> 4;          // m micro index
    const int m0  = blockIdx.y * 64;
    const int n0  = blockIdx.x * 64;
    const int lrow = tid >> 2;         // 0..63 : staging row
    const int lk   = (tid & 3) * 4;    // 0,4,8,12 : staging k offset

    float acc[4][4] = {};

    for (int kt = 0; kt < EMB; kt += 16) {
        float4 av = *(const float4*)&A[(size_t)(m0 + lrow) * EMB + kt + lk];
        float4 wv = *(const float4*)&W[(size_t)(n0 + lrow) * EMB + kt + lk];
        As[lk + 0][lrow] = av.x; As[lk + 1][lrow] = av.y;
        As[lk + 2][lrow] = av.z; As[lk + 3][lrow] = av.w;
        Ws[lk + 0][lrow] = wv.x; Ws[lk + 1][lrow] = wv.y;
        Ws[lk + 2][lrow] = wv.z; Ws[lk + 3][lrow] = wv.w;
        __syncthreads();
        #pragma unroll
        for (int kk = 0; kk < 16; ++kk) {
            float4 a = *(const float4*)&As[kk][ty * 4];
            float4 w = *(const float4*)&Ws[kk][tx * 4];
            acc[0][0] += a.x * w.x; acc[0][1] += a.x * w.y;
            acc[0][2] += a.x * w.z; acc[0][3] += a.x * w.w;
            acc[1][0] += a.y * w.x; acc[1][1] += a.y * w.y;
            acc[1][2] += a.y * w.z; acc[1][3] += a.y * w.w;
            acc[2][0] += a.z * w.x; acc[2][1] += a.z * w.y;
            acc[2][2] += a.z * w.z; acc[2][3] += a.z * w.w;
            acc[3][0] += a.w * w.x; acc[3][1] += a.w * w.y;
            acc[3][2] += a.w * w.z; acc[3][3] += a.w * w.w;
        }
        __syncthreads();
    }

    const int n = n0 + tx * 4;
    float bias[4];
    #pragma unroll
    for (int j = 0; j < 4; ++j) bias[j] = b_ih[n + j] + b_hh[n + j];

    #pragma unroll
    for (int i = 0; i < 4; ++i) {
        const int m = m0 + ty * 4 + i;
        const int b = m >> 9;          // m = b*512 + s
        const int s = m & 511;
        float4 o;
        o.x = acc[i][0] + bias[0];
        o.y = acc[i][1] + bias[1];
        o.z = acc[i][2] + bias[2];
        o.w = acc[i][3] + bias[3];
        *(float4*)&out[((size_t)(s * 64 + b) << 10) + n] = o;
    }
}

// ---------------------------------------------------------------------------
// Kernel B: one recurrence timestep.
//   h_t[b][j] = tanh( xp[t][b][j] + sum_k h_{t-1}[b][k] * W_hh[j][k] )
// xp lives in out[t][...] (written by kernel A) and is overwritten in place.
// Grid: 64 j-tiles x 4 b-tiles = 256 WGs (one per CU), 256 threads.
// Each WG: 16 batches x 16 outputs; h-slice + W-slice staged in LDS in
// 256-wide K chunks (33 KB LDS total).
// ---------------------------------------------------------------------------
__global__ __launch_bounds__(256) void rnn_step(
    const float* __restrict__ Whh,    // HID x HID row-major
    float* __restrict__ out,          // (S, B, HID)
    int t)
{
    const int tid = threadIdx.x;
    const int jl  = tid & 15;
    const int bl  = tid >> 4;
    const int j0  = blockIdx.x * 16;
    const int b0  = blockIdx.y * 16;
    const int j   = j0 + jl;
    const int b   = b0 + bl;

    float* cur = out + (size_t)t * (BATCH * HID);
    float z = cur[b * HID + j];        // xp for this (t,b,j)

    if (t > 0) {
        // pad 260: stride 1040B (16B aligned), bank group rotates 4/row
        __shared__ float Hs[16][260];
        __shared__ float Ws[16][260];
        const float* hp = out + (size_t)(t - 1) * (BATCH * HID);

        float4 acc = make_float4(0.f, 0.f, 0.f, 0.f);

        for (int kc = 0; kc < HID; kc += 256) {
            #pragma unroll
            for (int c = 0; c < 4; ++c) {
                const int fi  = c * 256 + tid;
                const int row = fi >> 6;          // 0..15
                const int kq  = (fi & 63) * 4;    // 0..252
                *(float4*)&Hs[row][kq] =
                    *(const float4*)&hp[(size_t)(b0 + row) * HID + kc + kq];
                *(float4*)&Ws[row][kq] =
                    *(const float4*)&Whh[(size_t)(j0 + row) * HID + kc + kq];
            }
            __syncthreads();
            #pragma unroll 16
            for (int kk = 0; kk < 64; ++kk) {
                float4 h4 = *(const float4*)&Hs[bl][kk * 4];
                float4 w4 = *(const float4*)&Ws[jl][kk * 4];
                acc.x += h4.x * w4.x;
                acc.y += h4.y * w4.y;
                acc.z += h4.z * w4.z;
                acc.w += h4.w * w4.w;
            }
            __syncthreads();
        }
        z += (acc.x + acc.y) + (acc.z + acc.w);
    }

    cur[b * HID + j] = tanhf(z);
}

// ---------------------------------------------------------------------------
extern "C" void kernel_launch(void* const* d_in, const int* in_sizes, int n_in,
                              void* d_out, int out_size, void* d_ws, size_t ws_size,
                              hipStream_t stream) {
    const float* embeds = (const float*)d_in[0];
    const float* W_ih   = (const float*)d_in[1];
    const float* W_hh   = (const float*)d_in[2];
    const float* b_ih   = (const float*)d_in[3];
    const float* b_hh   = (const float*)d_in[4];
    float* out = (float*)d_out;

    (void)d_ws; (void)ws_size; (void)in_sizes; (void)n_in; (void)out_size;

    // Phase 1: x_proj for all timesteps, written into d_out at [s][b][:]
    dim3 gA(HID / 64, (BATCH * SEQ) / 64);   // (16, 512)
    xproj_gemm<<<gA, 256, 0, stream>>>(embeds, W_ih, b_ih, b_hh, out);

    // Phase 2: sequential recurrence, one launch per timestep
    dim3 gB(HID / 16, BATCH / 16);           // (64, 4) = 256 WGs
    for (int t = 0; t < SEQ; ++t) {
        rnn_step<<<gB, 256, 0, stream>>>(W_hh, out, t);
    }
}